// Round 4
// baseline (105.046 us; speedup 1.0000x reference)
//
#include <hip/hip_runtime.h>

#define W_IMG 256
#define H_IMG 256
#define N_PIX 65536
#define M_GT  512
#define NB    4
#define TILES 256              // 16x16 grid of 16x16-pixel tiles
#define GTBLK 128              // gt blocks per sample (4 waves x 128 = 512 gt)
#define NBLK  (NB * (TILES + GTBLK))

constexpr float EPS   = 1e-6f;
constexpr float MAXD  = 362.03867196751236f;
constexpr float C_DEN = 2.7621343e-09f;   // float(EPS / max_dist)
#define BIGF 3.0e38f

// ---------------- single fused kernel ----------------
// blockIdx.x < TILES : term-1 for one 16x16 pixel tile (candidate-pruned gt scan)
// blockIdx.x >= TILES: term-2, one wave per gt (pass A window + guarded exact refine)
// epilogue           : last finished block does the deterministic final reduction
__global__ __launch_bounds__(256) void whd_fused(
    const float* __restrict__ prob, const int* __restrict__ gt,
    float* __restrict__ minU, float2* __restrict__ partials,
    unsigned int* __restrict__ counter, float* __restrict__ out)
{
  const int b    = blockIdx.y;
  const int tid  = threadIdx.x;
  const int lane = tid & 63;
  const int wave = tid >> 6;
  const int2* gtb = (const int2*)(gt + b * M_GT * 2);

  if (blockIdx.x < TILES) {
    // ---- term 1: one 16x16 pixel tile ----
    const int tile = blockIdx.x;
    const int row0 = (tile >> 4) << 4;
    const int col0 = (tile & 15) << 4;
    __shared__ float2 list[M_GT];
    __shared__ float  wred[4], ws1[4], ws0[4];
    __shared__ int    lcount;
    if (tid == 0) lcount = 0;

    int2 g0 = gtb[tid];
    int2 g1 = gtb[tid + 256];
    const float cy = row0 + 7.5f, cx = col0 + 7.5f;
    const float g0y = (float)g0.x, g0x = (float)g0.y;
    const float g1y = (float)g1.x, g1x = (float)g1.y;
    float dcy0 = g0y - cy, dcx0 = g0x - cx;
    float dcy1 = g1y - cy, dcx1 = g1x - cx;
    float d2c0 = fmaf(dcy0, dcy0, dcx0 * dcx0);   // exact on half-int grid < 2^18
    float d2c1 = fmaf(dcy1, dcy1, dcx1 * dcx1);
    float m = fminf(d2c0, d2c1);
#pragma unroll
    for (int s = 1; s < 64; s <<= 1) m = fminf(m, __shfl_xor(m, s, 64));
    if (lane == 0) wred[wave] = m;
    __syncthreads();                               // orders lcount=0 before atomics too
    float dmin2 = fminf(fminf(wred[0], wred[1]), fminf(wred[2], wred[3]));
    // candidate iff dcenter <= dmin_center + 2*tile_diag (+margin >> rounding)
    float rT = __builtin_amdgcn_sqrtf(dmin2) + 21.3f;
    float T  = rT * rT + 0.5f;

    bool pr0 = d2c0 <= T, pr1 = d2c1 <= T;
    unsigned long long m0 = __ballot(pr0);
    unsigned long long m1 = __ballot(pr1);
    int c0 = __popcll(m0), c1 = __popcll(m1);
    int base = 0;
    if (lane == 0) base = atomicAdd(&lcount, c0 + c1);
    base = __shfl(base, 0, 64);
    unsigned long long lt = (1ull << lane) - 1ull;
    if (pr0) list[base + __popcll(m0 & lt)]      = make_float2(g0y, g0x);
    if (pr1) list[base + c0 + __popcll(m1 & lt)] = make_float2(g1y, g1x);
    __syncthreads();
    const int ncand = lcount;

    const int py = row0 + (tid >> 4);
    const int px = col0 + (tid & 15);
    const float p  = prob[b * N_PIX + py * W_IMG + px];
    const float yf = (float)py, xf = (float)px;
    float md2 = BIGF;
    for (int c = 0; c < ncand; ++c) {
      float2 g = list[c];                       // broadcast read
      float dy = yf - g.x, dx = xf - g.y;
      md2 = fminf(md2, fmaf(dy, dy, dx * dx));  // exact integer d^2
    }
    float s1 = p * __builtin_amdgcn_sqrtf(md2);
    float s0 = p;
#pragma unroll
    for (int s = 1; s < 64; s <<= 1) {
      s1 += __shfl_xor(s1, s, 64);
      s0 += __shfl_xor(s0, s, 64);
    }
    if (lane == 0) { ws1[wave] = s1; ws0[wave] = s0; }
    __syncthreads();
    if (tid == 0)
      partials[b * TILES + tile] =
          make_float2(ws1[0] + ws1[1] + ws1[2] + ws1[3],
                      ws0[0] + ws0[1] + ws0[2] + ws0[3]);
  } else {
    // ---- term 2: one wave per gt ----
    const int j = (blockIdx.x - TILES) * 4 + wave;
    int2 g = gtb[j];
    const int gy = g.x, gx = g.y;
    float vmin = BIGF;
    // pass A: 16x16 window around gt -> upper bound U
#pragma unroll
    for (int k = 0; k < 4; ++k) {
      int idx = k * 64 + lane;
      int oy  = (idx >> 4) - 8;
      int ox  = (idx & 15) - 8;
      int y = gy + oy, x = gx + ox;
      if ((unsigned)y < H_IMG && (unsigned)x < W_IMG) {
        float p   = prob[b * N_PIX + y * W_IMG + x];
        float p2  = p * p;
        float w   = 1.0f / (p2 * p2 + C_DEN);
        float fdy = (float)oy, fdx = (float)ox;
        float d   = __builtin_amdgcn_sqrtf(fmaf(fdy, fdy, fdx * fdx));
        vmin = fminf(vmin, fmaf(d, w, EPS * w));   // (d+eps)/(p^4+eps/maxd)
      }
    }
#pragma unroll
    for (int s = 1; s < 64; s <<= 1) vmin = fminf(vmin, __shfl_xor(vmin, s, 64));
    // winner has d <= U*(1+3e-9); if R <= 7 the disk is inside the scanned window
    float Rf = vmin * 1.000001f + 0.01f;
    if (Rf > 7.0f) {                   // rare: exact refine within radius R
      Rf = fminf(Rf, 363.0f);
      int Ri = (int)Rf + 1;
      for (int yy = gy - Ri; yy <= gy + Ri; ++yy) {
        if ((unsigned)yy >= H_IMG) continue;
        float fdy = (float)(yy - gy);
        float dy2 = fdy * fdy;
        for (int xc = 0; xc <= 2 * Ri; xc += 64) {
          int xx = gx - Ri + xc + lane;
          if ((unsigned)xx < W_IMG) {
            float p   = prob[b * N_PIX + yy * W_IMG + xx];
            float p2  = p * p;
            float w   = 1.0f / (p2 * p2 + C_DEN);
            float fdx = (float)(xx - gx);
            float d   = __builtin_amdgcn_sqrtf(fmaf(fdx, fdx, dy2));
            vmin = fminf(vmin, fmaf(d, w, EPS * w));
          }
        }
      }
#pragma unroll
      for (int s = 1; s < 64; s <<= 1) vmin = fminf(vmin, __shfl_xor(vmin, s, 64));
    }
    if (lane == 0) minU[b * M_GT + j] = vmin;     // sole owner
  }

  // ---- completion protocol: last block does the final reduction ----
  __shared__ int isLast;
  __threadfence();                 // release this block's global writes (cross-XCD)
  __syncthreads();                 // drains mem ops of all threads before tid0 counts
  if (tid == 0) {
    unsigned int old = atomicAdd(counter, 1u);   // device-scope by default
    isLast = (old == (unsigned)(NBLK - 1));
  }
  __syncthreads();
  if (!isLast) return;
  __threadfence();                 // acquire: invalidate stale caches before reads

  const int rb = tid >> 6;         // one wave per sample
  __shared__ float t1[NB], t2[NB];
  float s2 = 0.f;
#pragma unroll
  for (int u = 0; u < M_GT / 64; ++u) {
    float v = minU[rb * M_GT + u * 64 + lane];
    v = fminf(fmaxf(v, 0.f), MAXD);
    s2 += v;
  }
  float s1 = 0.f, s0 = 0.f;
#pragma unroll
  for (int u = 0; u < TILES / 64; ++u) {
    float2 pp = partials[rb * TILES + u * 64 + lane];
    s1 += pp.x; s0 += pp.y;
  }
#pragma unroll
  for (int s = 1; s < 64; s <<= 1) {
    s2 += __shfl_xor(s2, s, 64);
    s1 += __shfl_xor(s1, s, 64);
    s0 += __shfl_xor(s0, s, 64);
  }
  if (lane == 0) {
    t1[rb] = s1 / (s0 + EPS);
    t2[rb] = s2 / (float)M_GT;
  }
  __syncthreads();
  if (tid == 0) {
    float a = 0.f, c = 0.f;
    for (int i = 0; i < NB; ++i) { a += t1[i]; c += t2[i]; }
    out[0] = a * 0.25f + c * 0.25f;
  }
}

extern "C" void kernel_launch(void* const* d_in, const int* in_sizes, int n_in,
                              void* d_out, int out_size, void* d_ws, size_t ws_size,
                              hipStream_t stream) {
  const float* prob = (const float*)d_in[0];
  const int*   gt   = (const int*)d_in[1];

  float*        minU     = (float*)d_ws;
  float2*       partials = (float2*)((char*)d_ws + (size_t)NB * M_GT * sizeof(float));
  unsigned int* counter  = (unsigned int*)((char*)d_ws +
                             (size_t)NB * M_GT * sizeof(float) +
                             (size_t)NB * TILES * sizeof(float2));

  hipMemsetAsync(counter, 0, sizeof(unsigned int), stream);
  whd_fused<<<dim3(TILES + GTBLK, NB), 256, 0, stream>>>(
      prob, gt, minU, partials, counter, (float*)d_out);
}

// Round 5
// 30.846 us; speedup vs baseline: 3.4055x; 3.4055x over previous
//
#include <hip/hip_runtime.h>

#define W_IMG 256
#define H_IMG 256
#define N_PIX 65536
#define M_GT  512
#define NB    4
#define T1BLK 32                 // term-1 blocks per sample (8 tiles each, 256 tiles)
#define T2BLK 16                 // term-2 blocks per sample (4 waves x 8 gt = 32 gt each)
#define BLKX  (T1BLK + T2BLK)    // 48 blocks per sample

constexpr float EPS   = 1e-6f;
constexpr float MAXD  = 362.03867196751236f;
constexpr float C_DEN = 2.7621343e-09f;   // float(EPS / max_dist)
#define BIGF 3.0e38f

// Relaxed agent-scope stores: write through to the device coherence point (sc1),
// so cross-XCD visibility needs NO buffer_wbl2. Drained by the s_waitcnt the
// compiler emits before s_barrier / before the counter atomic.
__device__ __forceinline__ void agent_store_f(float* p, float v) {
  __hip_atomic_store(p, v, __ATOMIC_RELAXED, __HIP_MEMORY_SCOPE_AGENT);
}
__device__ __forceinline__ void agent_store_f2(float2* p, float a, float c) {
  union { float2 f; unsigned long long u; } cv;
  cv.f = make_float2(a, c);
  __hip_atomic_store((unsigned long long*)p, cv.u, __ATOMIC_RELAXED,
                     __HIP_MEMORY_SCOPE_AGENT);
}

__global__ __launch_bounds__(256) void whd_fused(
    const float* __restrict__ prob, const int* __restrict__ gt,
    float* __restrict__ minU, float2* __restrict__ partials,
    float2* __restrict__ sres, unsigned int* __restrict__ cnt,
    float* __restrict__ out)
{
  const int b    = blockIdx.y;
  const int xb   = blockIdx.x;
  const int tid  = threadIdx.x;
  const int lane = tid & 63;
  const int wave = tid >> 6;
  const int2* gtb = (const int2*)(gt + b * M_GT * 2);

  if (xb < T1BLK) {
    // ---- term 1: 8 16x16-pixel tiles, candidate-pruned gt scan ----
    __shared__ float2 list[M_GT];
    __shared__ float  wred[4], ws1[4], ws0[4];
    __shared__ int    lcount;

    int2 g0 = gtb[tid];
    int2 g1 = gtb[tid + 256];
    const float g0y = (float)g0.x, g0x = (float)g0.y;
    const float g1y = (float)g1.x, g1x = (float)g1.y;

    float pv[8];                        // prefetch this block's 8 tiles of p
#pragma unroll
    for (int t = 0; t < 8; ++t) {
      int tile = xb * 8 + t;
      int py = ((tile >> 4) << 4) + (tid >> 4);
      int px = ((tile & 15) << 4) + (tid & 15);
      pv[t] = prob[b * N_PIX + py * W_IMG + px];
    }

    float s1 = 0.f, s0 = 0.f;
    for (int t = 0; t < 8; ++t) {
      const int tile = xb * 8 + t;
      const int row0 = (tile >> 4) << 4;
      const int col0 = (tile & 15) << 4;
      const float cy = row0 + 7.5f, cx = col0 + 7.5f;
      float dcy0 = g0y - cy, dcx0 = g0x - cx;
      float dcy1 = g1y - cy, dcx1 = g1x - cx;
      float d2c0 = fmaf(dcy0, dcy0, dcx0 * dcx0);   // exact: half-int grid < 2^18
      float d2c1 = fmaf(dcy1, dcy1, dcx1 * dcx1);
      float m = fminf(d2c0, d2c1);
#pragma unroll
      for (int s = 1; s < 64; s <<= 1) m = fminf(m, __shfl_xor(m, s, 64));
      if (lane == 0) wred[wave] = m;
      if (tid == 0) lcount = 0;
      __syncthreads();                               // (a) wred+reset visible
      float dmin2 = fminf(fminf(wred[0], wred[1]), fminf(wred[2], wred[3]));
      // candidate iff dcenter <= dmin_center + 2*half_diag (margins >> rounding)
      float rT = __builtin_amdgcn_sqrtf(dmin2) + 21.3f;
      float T  = rT * rT + 0.5f;

      bool pr0 = d2c0 <= T, pr1 = d2c1 <= T;
      unsigned long long m0 = __ballot(pr0);
      unsigned long long m1 = __ballot(pr1);
      int c0 = __popcll(m0), c1 = __popcll(m1);
      int base = 0;
      if (lane == 0) base = atomicAdd(&lcount, c0 + c1);
      base = __shfl(base, 0, 64);
      unsigned long long lt = (1ull << lane) - 1ull;
      if (pr0) list[base + __popcll(m0 & lt)]      = make_float2(g0y, g0x);
      if (pr1) list[base + c0 + __popcll(m1 & lt)] = make_float2(g1y, g1x);
      __syncthreads();                               // (b) list built
      const int ncand = lcount;

      const float yf = (float)(row0 + (tid >> 4));
      const float xf = (float)(col0 + (tid & 15));
      float md2 = BIGF;
      for (int c = 0; c < ncand; ++c) {
        float2 g = list[c];                          // broadcast read
        float dy = yf - g.x, dx = xf - g.y;
        md2 = fminf(md2, fmaf(dy, dy, dx * dx));     // exact integer d^2
      }
      s1 += pv[t] * __builtin_amdgcn_sqrtf(md2);
      s0 += pv[t];
      __syncthreads();                               // (c) list/lcount reusable
    }
#pragma unroll
    for (int s = 1; s < 64; s <<= 1) {
      s1 += __shfl_xor(s1, s, 64);
      s0 += __shfl_xor(s0, s, 64);
    }
    if (lane == 0) { ws1[wave] = s1; ws0[wave] = s0; }
    __syncthreads();
    if (tid == 0)
      agent_store_f2(&partials[b * T1BLK + xb],
                     ws1[0] + ws1[1] + ws1[2] + ws1[3],
                     ws0[0] + ws0[1] + ws0[2] + ws0[3]);
  } else {
    // ---- term 2: 4 waves x 8 gt each; pass-A window + guarded exact refine ----
    const int jbase = (xb - T1BLK) * 32 + wave * 8;
    for (int gi = 0; gi < 8; ++gi) {
      const int j = jbase + gi;
      int2 g = gtb[j];
      const int gy = g.x, gx = g.y;
      float vmin = BIGF;
#pragma unroll
      for (int k = 0; k < 4; ++k) {
        int idx = k * 64 + lane;
        int oy  = (idx >> 4) - 8;
        int ox  = (idx & 15) - 8;
        int y = gy + oy, x = gx + ox;
        if ((unsigned)y < H_IMG && (unsigned)x < W_IMG) {
          float p   = prob[b * N_PIX + y * W_IMG + x];
          float p2  = p * p;
          float w   = 1.0f / (p2 * p2 + C_DEN);
          float fdy = (float)oy, fdx = (float)ox;
          float d   = __builtin_amdgcn_sqrtf(fmaf(fdy, fdy, fdx * fdx));
          vmin = fminf(vmin, fmaf(d, w, EPS * w));   // (d+eps)/(p^4+eps/maxd)
        }
      }
#pragma unroll
      for (int s = 1; s < 64; s <<= 1) vmin = fminf(vmin, __shfl_xor(vmin, s, 64));
      // winner has d <= U*(1+3e-9); if R <= 7 the disk was inside the window
      float Rf = vmin * 1.000001f + 0.01f;
      if (Rf > 7.0f) {
        Rf = fminf(Rf, 363.0f);
        int Ri = (int)Rf + 1;
        for (int yy = gy - Ri; yy <= gy + Ri; ++yy) {
          if ((unsigned)yy >= H_IMG) continue;
          float fdy = (float)(yy - gy);
          float dy2 = fdy * fdy;
          for (int xc = 0; xc <= 2 * Ri; xc += 64) {
            int xx = gx - Ri + xc + lane;
            if ((unsigned)xx < W_IMG) {
              float p   = prob[b * N_PIX + yy * W_IMG + xx];
              float p2  = p * p;
              float w   = 1.0f / (p2 * p2 + C_DEN);
              float fdx = (float)(xx - gx);
              float d   = __builtin_amdgcn_sqrtf(fmaf(fdx, fdx, dy2));
              vmin = fminf(vmin, fmaf(d, w, EPS * w));
            }
          }
        }
#pragma unroll
        for (int s = 1; s < 64; s <<= 1) vmin = fminf(vmin, __shfl_xor(vmin, s, 64));
      }
      if (lane == 0) agent_store_f(&minU[b * M_GT + j], vmin);  // sole owner
    }
  }

  // ---- completion: per-sample last block reduces its sample; global last combines ----
  __shared__ unsigned int ordS;
  __syncthreads();   // compiler drains vmcnt before barrier -> sc1 stores visible
  if (tid == 0)
    ordS = __hip_atomic_fetch_add(&cnt[b * 16], 1u, __ATOMIC_RELAXED,
                                  __HIP_MEMORY_SCOPE_AGENT);
  __syncthreads();
  if (ordS != (unsigned)(BLKX - 1)) return;

  __builtin_amdgcn_fence(__ATOMIC_ACQUIRE, "agent");  // buffer_inv: plain reads safe
  __shared__ float ls2[4];
  __shared__ float2 lp[T1BLK];
  float v0 = minU[b * M_GT + tid];
  float v1 = minU[b * M_GT + 256 + tid];
  float s2 = fminf(fmaxf(v0, 0.f), MAXD) + fminf(fmaxf(v1, 0.f), MAXD);
#pragma unroll
  for (int s = 1; s < 64; s <<= 1) s2 += __shfl_xor(s2, s, 64);
  if (lane == 0) ls2[wave] = s2;
  if (tid < T1BLK) lp[tid] = partials[b * T1BLK + tid];
  __syncthreads();
  if (tid == 0) {
    float t2 = (ls2[0] + ls2[1] + ls2[2] + ls2[3]) / (float)M_GT;
    float a = 0.f, c = 0.f;
    for (int i = 0; i < T1BLK; ++i) { a += lp[i].x; c += lp[i].y; }  // fixed order
    float t1 = a / (c + EPS);
    agent_store_f2(&sres[b], t1, t2);
    asm volatile("s_waitcnt vmcnt(0)" ::: "memory");   // sres visible before count
    unsigned int ordG = __hip_atomic_fetch_add(&cnt[64], 1u, __ATOMIC_RELAXED,
                                               __HIP_MEMORY_SCOPE_AGENT);
    if (ordG == (unsigned)(NB - 1)) {
      __builtin_amdgcn_fence(__ATOMIC_ACQUIRE, "agent");
      float aa = 0.f, cc = 0.f;
      for (int i = 0; i < NB; ++i) { float2 r = sres[i]; aa += r.x; cc += r.y; }
      out[0] = aa * 0.25f + cc * 0.25f;
    }
  }
}

extern "C" void kernel_launch(void* const* d_in, const int* in_sizes, int n_in,
                              void* d_out, int out_size, void* d_ws, size_t ws_size,
                              hipStream_t stream) {
  const float* prob = (const float*)d_in[0];
  const int*   gt   = (const int*)d_in[1];

  char* ws = (char*)d_ws;
  float*        minU     = (float*)ws;                              // NB*512 f
  float2*       partials = (float2*)(ws + 8192);                    // NB*32 f2
  float2*       sres     = (float2*)(ws + 8192 + 1024);             // NB f2
  unsigned int* cnt      = (unsigned int*)(ws + 8192 + 1024 + 64);  // 65 u32

  hipMemsetAsync(cnt, 0, 65 * sizeof(unsigned int), stream);
  whd_fused<<<dim3(BLKX, NB), 256, 0, stream>>>(
      prob, gt, minU, partials, sres, cnt, (float*)d_out);
}

// Round 6
// 22.944 us; speedup vs baseline: 4.5784x; 1.3444x over previous
//
#include <hip/hip_runtime.h>

#define W_IMG 256
#define H_IMG 256
#define N_PIX 65536
#define M_GT  512
#define NB    4
#define TILES 256               // 256 term-1 blocks/sample: one 16x16 tile each
#define T2BLK 128               // 128 term-2 blocks/sample: 4 waves x 1 gt = 512 gt
#define BLKX  (TILES + T2BLK)   // 384 blocks per sample

constexpr float EPS   = 1e-6f;
constexpr float MAXD  = 362.03867196751236f;
constexpr float C_DEN = 2.7621343e-09f;   // float(EPS / max_dist)
#define BIGF 3.0e38f

// Relaxed agent-scope stores: write through to the device coherence point (sc1);
// cross-XCD visibility without buffer_wbl2. The compiler's s_waitcnt vmcnt(0)
// before s_barrier drains them prior to the arrival atomic.
__device__ __forceinline__ void agent_store_f(float* p, float v) {
  __hip_atomic_store(p, v, __ATOMIC_RELAXED, __HIP_MEMORY_SCOPE_AGENT);
}
__device__ __forceinline__ void agent_store_f2(float2* p, float a, float c) {
  union { float2 f; unsigned long long u; } cv;
  cv.f = make_float2(a, c);
  __hip_atomic_store((unsigned long long*)p, cv.u, __ATOMIC_RELAXED,
                     __HIP_MEMORY_SCOPE_AGENT);
}

__global__ __launch_bounds__(256) void whd_fused(
    const float* __restrict__ prob, const int* __restrict__ gt,
    float* __restrict__ minU, float2* __restrict__ partials,
    float2* __restrict__ sres, unsigned int* __restrict__ cnt,
    float* __restrict__ out)
{
  const int b    = blockIdx.y;
  const int xb   = blockIdx.x;
  const int tid  = threadIdx.x;
  const int lane = tid & 63;
  const int wave = tid >> 6;
  const int2* gtb = (const int2*)(gt + b * M_GT * 2);

  if (xb < TILES) {
    // ---- term 1: one 16x16 pixel tile, candidate-pruned gt scan ----
    const int tile = xb;
    const int row0 = (tile >> 4) << 4;
    const int col0 = (tile & 15) << 4;
    __shared__ float2 list[M_GT];
    __shared__ float  wred[4], ws1[4], ws0[4];
    __shared__ int    lcount;
    if (tid == 0) lcount = 0;

    int2 g0 = gtb[tid];
    int2 g1 = gtb[tid + 256];
    const float cy = row0 + 7.5f, cx = col0 + 7.5f;
    const float g0y = (float)g0.x, g0x = (float)g0.y;
    const float g1y = (float)g1.x, g1x = (float)g1.y;
    float dcy0 = g0y - cy, dcx0 = g0x - cx;
    float dcy1 = g1y - cy, dcx1 = g1x - cx;
    float d2c0 = fmaf(dcy0, dcy0, dcx0 * dcx0);   // exact: half-int grid < 2^18
    float d2c1 = fmaf(dcy1, dcy1, dcx1 * dcx1);
    float m = fminf(d2c0, d2c1);
#pragma unroll
    for (int s = 1; s < 64; s <<= 1) m = fminf(m, __shfl_xor(m, s, 64));
    if (lane == 0) wred[wave] = m;
    __syncthreads();                               // wred + lcount reset visible
    float dmin2 = fminf(fminf(wred[0], wred[1]), fminf(wred[2], wred[3]));
    // candidate iff dcenter <= dmin_center + 2*half_diag (margin >> all rounding)
    float rT = __builtin_amdgcn_sqrtf(dmin2) + 21.3f;
    float T  = rT * rT + 0.5f;

    bool pr0 = d2c0 <= T, pr1 = d2c1 <= T;
    unsigned long long m0 = __ballot(pr0);
    unsigned long long m1 = __ballot(pr1);
    int c0 = __popcll(m0), c1 = __popcll(m1);
    int base = 0;
    if (lane == 0) base = atomicAdd(&lcount, c0 + c1);
    base = __shfl(base, 0, 64);
    unsigned long long lt = (1ull << lane) - 1ull;
    if (pr0) list[base + __popcll(m0 & lt)]      = make_float2(g0y, g0x);
    if (pr1) list[base + c0 + __popcll(m1 & lt)] = make_float2(g1y, g1x);
    __syncthreads();
    const int ncand = lcount;

    const int py = row0 + (tid >> 4);
    const int px = col0 + (tid & 15);
    const float p  = prob[b * N_PIX + py * W_IMG + px];
    const float yf = (float)py, xf = (float)px;
    float md2 = BIGF;
    for (int c = 0; c < ncand; ++c) {
      float2 g = list[c];                          // broadcast read
      float dy = yf - g.x, dx = xf - g.y;
      md2 = fminf(md2, fmaf(dy, dy, dx * dx));     // exact integer d^2
    }
    float s1 = p * __builtin_amdgcn_sqrtf(md2);
    float s0 = p;
#pragma unroll
    for (int s = 1; s < 64; s <<= 1) {
      s1 += __shfl_xor(s1, s, 64);
      s0 += __shfl_xor(s0, s, 64);
    }
    if (lane == 0) { ws1[wave] = s1; ws0[wave] = s0; }
    __syncthreads();
    if (tid == 0)
      agent_store_f2(&partials[b * TILES + tile],
                     ws1[0] + ws1[1] + ws1[2] + ws1[3],
                     ws0[0] + ws0[1] + ws0[2] + ws0[3]);
  } else {
    // ---- term 2: one wave per gt; pass-A 16x16 window + guarded exact refine ----
    const int j = (xb - TILES) * 4 + wave;
    int2 g = gtb[j];
    const int gy = g.x, gx = g.y;
    float vmin = BIGF;
#pragma unroll
    for (int k = 0; k < 4; ++k) {
      int idx = k * 64 + lane;
      int oy  = (idx >> 4) - 8;
      int ox  = (idx & 15) - 8;
      int y = gy + oy, x = gx + ox;
      if ((unsigned)y < H_IMG && (unsigned)x < W_IMG) {
        float p   = prob[b * N_PIX + y * W_IMG + x];
        float p2  = p * p;
        float w   = 1.0f / (p2 * p2 + C_DEN);
        float fdy = (float)oy, fdx = (float)ox;
        float d   = __builtin_amdgcn_sqrtf(fmaf(fdy, fdy, fdx * fdx));
        vmin = fminf(vmin, fmaf(d, w, EPS * w));   // (d+eps)/(p^4+eps/maxd)
      }
    }
#pragma unroll
    for (int s = 1; s < 64; s <<= 1) vmin = fminf(vmin, __shfl_xor(vmin, s, 64));
    // winner has d <= U*(1+3e-9); if R <= 7 the disk was inside the scanned window
    float Rf = vmin * 1.000001f + 0.01f;
    if (Rf > 7.0f) {
      Rf = fminf(Rf, 363.0f);
      int Ri = (int)Rf + 1;
      for (int yy = gy - Ri; yy <= gy + Ri; ++yy) {
        if ((unsigned)yy >= H_IMG) continue;
        float fdy = (float)(yy - gy);
        float dy2 = fdy * fdy;
        for (int xc = 0; xc <= 2 * Ri; xc += 64) {
          int xx = gx - Ri + xc + lane;
          if ((unsigned)xx < W_IMG) {
            float p   = prob[b * N_PIX + yy * W_IMG + xx];
            float p2  = p * p;
            float w   = 1.0f / (p2 * p2 + C_DEN);
            float fdx = (float)(xx - gx);
            float d   = __builtin_amdgcn_sqrtf(fmaf(fdx, fdx, dy2));
            vmin = fminf(vmin, fmaf(d, w, EPS * w));
          }
        }
      }
#pragma unroll
      for (int s = 1; s < 64; s <<= 1) vmin = fminf(vmin, __shfl_xor(vmin, s, 64));
    }
    if (lane == 0) agent_store_f(&minU[b * M_GT + j], vmin);   // sole owner
  }

  // ---- completion: per-sample last block reduces; global last combines ----
  __shared__ unsigned int ordS;
  __syncthreads();   // pre-barrier vmcnt(0) drains the sc1 result stores
  if (tid == 0)
    ordS = __hip_atomic_fetch_add(&cnt[b * 16], 1u, __ATOMIC_RELAXED,
                                  __HIP_MEMORY_SCOPE_AGENT);
  __syncthreads();
  if (ordS != (unsigned)(BLKX - 1)) return;

  __builtin_amdgcn_fence(__ATOMIC_ACQUIRE, "agent");  // inv caches: plain reads safe
  __shared__ float ls2[4], la[4], lc[4];
  float v0 = minU[b * M_GT + tid];
  float v1 = minU[b * M_GT + 256 + tid];
  float s2 = fminf(fmaxf(v0, 0.f), MAXD) + fminf(fmaxf(v1, 0.f), MAXD);
  float2 pp = partials[b * TILES + tid];              // one tile partial per thread
  float s1 = pp.x, s0 = pp.y;
#pragma unroll
  for (int s = 1; s < 64; s <<= 1) {
    s2 += __shfl_xor(s2, s, 64);
    s1 += __shfl_xor(s1, s, 64);
    s0 += __shfl_xor(s0, s, 64);
  }
  if (lane == 0) { ls2[wave] = s2; la[wave] = s1; lc[wave] = s0; }
  __syncthreads();
  if (tid == 0) {
    float t2 = (ls2[0] + ls2[1] + ls2[2] + ls2[3]) / (float)M_GT;
    float a  = la[0] + la[1] + la[2] + la[3];
    float c  = lc[0] + lc[1] + lc[2] + lc[3];
    float t1 = a / (c + EPS);
    agent_store_f2(&sres[b], t1, t2);
    asm volatile("s_waitcnt vmcnt(0)" ::: "memory");  // sres visible before count
    unsigned int ordG = __hip_atomic_fetch_add(&cnt[64], 1u, __ATOMIC_RELAXED,
                                               __HIP_MEMORY_SCOPE_AGENT);
    if (ordG == (unsigned)(NB - 1)) {
      __builtin_amdgcn_fence(__ATOMIC_ACQUIRE, "agent");
      float aa = 0.f, cc = 0.f;
      for (int i = 0; i < NB; ++i) { float2 r = sres[i]; aa += r.x; cc += r.y; }
      out[0] = aa * 0.25f + cc * 0.25f;
    }
  }
}

extern "C" void kernel_launch(void* const* d_in, const int* in_sizes, int n_in,
                              void* d_out, int out_size, void* d_ws, size_t ws_size,
                              hipStream_t stream) {
  const float* prob = (const float*)d_in[0];
  const int*   gt   = (const int*)d_in[1];

  char* ws = (char*)d_ws;
  float*        minU     = (float*)ws;                               // NB*512 f = 8 KB
  float2*       partials = (float2*)(ws + 8192);                     // NB*256 f2 = 8 KB
  float2*       sres     = (float2*)(ws + 8192 + 8192);              // NB f2
  unsigned int* cnt      = (unsigned int*)(ws + 8192 + 8192 + 64);   // 65 u32

  hipMemsetAsync(cnt, 0, 65 * sizeof(unsigned int), stream);
  whd_fused<<<dim3(BLKX, NB), 256, 0, stream>>>(
      prob, gt, minU, partials, sres, cnt, (float*)d_out);
}

// Round 7
// 12.094 us; speedup vs baseline: 8.6857x; 1.8971x over previous
//
#include <hip/hip_runtime.h>

#define W_IMG 256
#define H_IMG 256
#define N_PIX 65536
#define M_GT  512
#define NB    4
#define TILES 256               // 256 term-1 blocks/sample: one 16x16 tile each
#define T2BLK 128               // 128 term-2 blocks/sample: 4 waves x 1 gt = 512 gt
#define BLKX  (TILES + T2BLK)   // 384 blocks per sample

constexpr float EPS   = 1e-6f;
constexpr float MAXD  = 362.03867196751236f;
constexpr float C_DEN = 2.7621343e-09f;   // float(EPS / max_dist)
#define BIGF 3.0e38f

// ---------------- K1: all pair work; every output slot has one owner ----------------
__global__ __launch_bounds__(256) void whd_work(
    const float* __restrict__ prob, const int* __restrict__ gt,
    float* __restrict__ minU, float2* __restrict__ partials)
{
  const int b    = blockIdx.y;
  const int xb   = blockIdx.x;
  const int tid  = threadIdx.x;
  const int lane = tid & 63;
  const int wave = tid >> 6;
  const int2* gtb = (const int2*)(gt + b * M_GT * 2);

  if (xb < TILES) {
    // ---- term 1: one 16x16 pixel tile, candidate-pruned gt scan ----
    const int tile = xb;
    const int row0 = (tile >> 4) << 4;
    const int col0 = (tile & 15) << 4;
    __shared__ float2 list[M_GT];
    __shared__ float  wred[4], ws1[4], ws0[4];
    __shared__ int    lcount;
    if (tid == 0) lcount = 0;

    int2 g0 = gtb[tid];
    int2 g1 = gtb[tid + 256];
    const float cy = row0 + 7.5f, cx = col0 + 7.5f;
    const float g0y = (float)g0.x, g0x = (float)g0.y;
    const float g1y = (float)g1.x, g1x = (float)g1.y;
    float dcy0 = g0y - cy, dcx0 = g0x - cx;
    float dcy1 = g1y - cy, dcx1 = g1x - cx;
    float d2c0 = fmaf(dcy0, dcy0, dcx0 * dcx0);   // exact: half-int grid < 2^18
    float d2c1 = fmaf(dcy1, dcy1, dcx1 * dcx1);
    float m = fminf(d2c0, d2c1);
#pragma unroll
    for (int s = 1; s < 64; s <<= 1) m = fminf(m, __shfl_xor(m, s, 64));
    if (lane == 0) wred[wave] = m;
    __syncthreads();                               // wred + lcount reset visible
    float dmin2 = fminf(fminf(wred[0], wred[1]), fminf(wred[2], wred[3]));
    // candidate iff dcenter <= dmin_center + 2*half_diag (margin >> all rounding)
    float rT = __builtin_amdgcn_sqrtf(dmin2) + 21.3f;
    float T  = rT * rT + 0.5f;

    bool pr0 = d2c0 <= T, pr1 = d2c1 <= T;
    unsigned long long m0 = __ballot(pr0);
    unsigned long long m1 = __ballot(pr1);
    int c0 = __popcll(m0), c1 = __popcll(m1);
    int base = 0;
    if (lane == 0) base = atomicAdd(&lcount, c0 + c1);
    base = __shfl(base, 0, 64);
    unsigned long long lt = (1ull << lane) - 1ull;
    if (pr0) list[base + __popcll(m0 & lt)]      = make_float2(g0y, g0x);
    if (pr1) list[base + c0 + __popcll(m1 & lt)] = make_float2(g1y, g1x);
    __syncthreads();
    const int ncand = lcount;

    const int py = row0 + (tid >> 4);
    const int px = col0 + (tid & 15);
    const float p  = prob[b * N_PIX + py * W_IMG + px];
    const float yf = (float)py, xf = (float)px;
    float md2 = BIGF;
    for (int c = 0; c < ncand; ++c) {
      float2 g = list[c];                          // broadcast read
      float dy = yf - g.x, dx = xf - g.y;
      md2 = fminf(md2, fmaf(dy, dy, dx * dx));     // exact integer d^2
    }
    float s1 = p * __builtin_amdgcn_sqrtf(md2);
    float s0 = p;
#pragma unroll
    for (int s = 1; s < 64; s <<= 1) {
      s1 += __shfl_xor(s1, s, 64);
      s0 += __shfl_xor(s0, s, 64);
    }
    if (lane == 0) { ws1[wave] = s1; ws0[wave] = s0; }
    __syncthreads();
    if (tid == 0)
      partials[b * TILES + tile] =
          make_float2(ws1[0] + ws1[1] + ws1[2] + ws1[3],
                      ws0[0] + ws0[1] + ws0[2] + ws0[3]);
  } else {
    // ---- term 2: one wave per gt; pass-A 16x16 window + guarded exact refine ----
    const int j = (xb - TILES) * 4 + wave;
    int2 g = gtb[j];
    const int gy = g.x, gx = g.y;
    float vmin = BIGF;
#pragma unroll
    for (int k = 0; k < 4; ++k) {
      int idx = k * 64 + lane;
      int oy  = (idx >> 4) - 8;
      int ox  = (idx & 15) - 8;
      int y = gy + oy, x = gx + ox;
      if ((unsigned)y < H_IMG && (unsigned)x < W_IMG) {
        float p   = prob[b * N_PIX + y * W_IMG + x];
        float p2  = p * p;
        float w   = 1.0f / (p2 * p2 + C_DEN);
        float fdy = (float)oy, fdx = (float)ox;
        float d   = __builtin_amdgcn_sqrtf(fmaf(fdy, fdy, fdx * fdx));
        vmin = fminf(vmin, fmaf(d, w, EPS * w));   // (d+eps)/(p^4+eps/maxd)
      }
    }
#pragma unroll
    for (int s = 1; s < 64; s <<= 1) vmin = fminf(vmin, __shfl_xor(vmin, s, 64));
    // winner has d <= U*(1+3e-9); if R <= 7 the disk was inside the scanned window
    float Rf = vmin * 1.000001f + 0.01f;
    if (Rf > 7.0f) {
      Rf = fminf(Rf, 363.0f);
      int Ri = (int)Rf + 1;
      for (int yy = gy - Ri; yy <= gy + Ri; ++yy) {
        if ((unsigned)yy >= H_IMG) continue;
        float fdy = (float)(yy - gy);
        float dy2 = fdy * fdy;
        for (int xc = 0; xc <= 2 * Ri; xc += 64) {
          int xx = gx - Ri + xc + lane;
          if ((unsigned)xx < W_IMG) {
            float p   = prob[b * N_PIX + yy * W_IMG + xx];
            float p2  = p * p;
            float w   = 1.0f / (p2 * p2 + C_DEN);
            float fdx = (float)(xx - gx);
            float d   = __builtin_amdgcn_sqrtf(fmaf(fdx, fdx, dy2));
            vmin = fminf(vmin, fmaf(d, w, EPS * w));
          }
        }
      }
#pragma unroll
      for (int s = 1; s < 64; s <<= 1) vmin = fminf(vmin, __shfl_xor(vmin, s, 64));
    }
    if (lane == 0) minU[b * M_GT + j] = vmin;      // sole owner
  }
}

// ---------------- K2: single-block fixed-order final reduction ----------------
__global__ __launch_bounds__(256) void whd_final(
    const float* __restrict__ minU,
    const float2* __restrict__ partials,
    float* __restrict__ out)
{
  const int tid  = threadIdx.x;
  const int lane = tid & 63;
  const int b    = tid >> 6;        // one wave per sample
  __shared__ float t1[NB], t2[NB];

  // term 2: mean of clipped per-gt mins (8 per lane, fixed order)
  float s2 = 0.f;
#pragma unroll
  for (int u = 0; u < M_GT / 64; ++u) {
    float v = minU[b * M_GT + u * 64 + lane];
    v = fminf(fmaxf(v, 0.f), MAXD);
    s2 += v;
  }
  // term 1: 256 per-tile partials (4 per lane, fixed order)
  float s1 = 0.f, s0 = 0.f;
#pragma unroll
  for (int u = 0; u < TILES / 64; ++u) {
    float2 pp = partials[b * TILES + u * 64 + lane];
    s1 += pp.x; s0 += pp.y;
  }
#pragma unroll
  for (int m = 1; m < 64; m <<= 1) {
    s2 += __shfl_xor(s2, m, 64);
    s1 += __shfl_xor(s1, m, 64);
    s0 += __shfl_xor(s0, m, 64);
  }
  if (lane == 0) {
    t1[b] = s1 / (s0 + EPS);
    t2[b] = s2 / (float)M_GT;
  }
  __syncthreads();
  if (tid == 0) {
    float a = 0.f, c = 0.f;
    for (int i = 0; i < NB; ++i) { a += t1[i]; c += t2[i]; }
    out[0] = a * 0.25f + c * 0.25f;
  }
}

extern "C" void kernel_launch(void* const* d_in, const int* in_sizes, int n_in,
                              void* d_out, int out_size, void* d_ws, size_t ws_size,
                              hipStream_t stream) {
  const float* prob = (const float*)d_in[0];
  const int*   gt   = (const int*)d_in[1];

  char* ws = (char*)d_ws;
  float*  minU     = (float*)ws;                    // NB*512 floats = 8 KB
  float2* partials = (float2*)(ws + 8192);          // NB*256 float2 = 8 KB

  whd_work<<<dim3(BLKX, NB), 256, 0, stream>>>(prob, gt, minU, partials);
  whd_final<<<1, 256, 0, stream>>>(minU, partials, (float*)d_out);
}

// Round 8
// 11.609 us; speedup vs baseline: 9.0484x; 1.0418x over previous
//
#include <hip/hip_runtime.h>

#define W_IMG 256
#define H_IMG 256
#define N_PIX 65536
#define M_GT  512
#define NB    4
#define TILES 256               // 256 term-1 blocks/sample: one 16x16 tile each
#define T2BLK 128               // 128 term-2 blocks/sample: 4 waves x 1 gt = 512 gt
#define BLKX  (TILES + T2BLK)   // 384 blocks per sample

constexpr float EPS   = 1e-6f;
constexpr float MAXD  = 362.03867196751236f;
constexpr float C_DEN = 2.7621343e-09f;   // float(EPS / max_dist)
#define BIGF 3.0e38f

// ---------------- K1: all pair work; every output slot has one owner ----------------
__global__ __launch_bounds__(256) void whd_work(
    const float* __restrict__ prob, const int* __restrict__ gt,
    float* __restrict__ minU, float2* __restrict__ partials)
{
  const int b    = blockIdx.y;
  const int xb   = blockIdx.x;
  const int tid  = threadIdx.x;
  const int lane = tid & 63;
  const int wave = tid >> 6;

  if (xb < TILES) {
    // ---- term 1: one 16x16 pixel tile, candidate-pruned gt scan ----
    const int tile = xb;
    const int row0 = (tile >> 4) << 4;
    const int col0 = (tile & 15) << 4;
    __shared__ float2 list[M_GT];
    __shared__ float  wred[4], ws1[4], ws0[4];
    __shared__ int    lcount;
    if (tid == 0) lcount = 0;

    // prefetch this thread's pixel early: latency hides under the prune phase
    const int py = row0 + (tid >> 4);
    const int px = col0 + (tid & 15);
    const float p = prob[b * N_PIX + py * W_IMG + px];

    // one dwordx4 per thread: gt points 2*tid and 2*tid+1
    const int4* gt4 = (const int4*)(gt + b * M_GT * 2);
    int4 gp = gt4[tid];
    const float g0y = (float)gp.x, g0x = (float)gp.y;
    const float g1y = (float)gp.z, g1x = (float)gp.w;

    const float cy = row0 + 7.5f, cx = col0 + 7.5f;
    float dcy0 = g0y - cy, dcx0 = g0x - cx;
    float dcy1 = g1y - cy, dcx1 = g1x - cx;
    float d2c0 = fmaf(dcy0, dcy0, dcx0 * dcx0);   // exact: half-int grid < 2^18
    float d2c1 = fmaf(dcy1, dcy1, dcx1 * dcx1);
    float m = fminf(d2c0, d2c1);
#pragma unroll
    for (int s = 1; s < 64; s <<= 1) m = fminf(m, __shfl_xor(m, s, 64));
    if (lane == 0) wred[wave] = m;
    __syncthreads();                               // wred + lcount reset visible
    float dmin2 = fminf(fminf(wred[0], wred[1]), fminf(wred[2], wred[3]));
    // candidate iff dcenter <= dmin_center + 2*half_diag (margin >> all rounding)
    float rT = __builtin_amdgcn_sqrtf(dmin2) + 21.3f;
    float T  = rT * rT + 0.5f;

    bool pr0 = d2c0 <= T, pr1 = d2c1 <= T;
    unsigned long long m0 = __ballot(pr0);
    unsigned long long m1 = __ballot(pr1);
    int c0 = __popcll(m0), c1 = __popcll(m1);
    int base = 0;
    if (lane == 0) base = atomicAdd(&lcount, c0 + c1);
    base = __shfl(base, 0, 64);
    unsigned long long lt = (1ull << lane) - 1ull;
    if (pr0) list[base + __popcll(m0 & lt)]      = make_float2(g0y, g0x);
    if (pr1) list[base + c0 + __popcll(m1 & lt)] = make_float2(g1y, g1x);
    __syncthreads();
    const int ncand = lcount;                      // >= 1 (nearest gt always passes)

    const float yf = (float)py, xf = (float)px;
    float md2 = BIGF;
    const int nc4 = (ncand + 3) & ~3;
    for (int c = 0; c < nc4; c += 4) {             // x4 unroll, clamped (uniform) idx
      int i1 = min(c + 1, ncand - 1);
      int i2 = min(c + 2, ncand - 1);
      int i3 = min(c + 3, ncand - 1);
      float2 ga = list[c],  gb = list[i1];         // broadcast reads
      float2 gc = list[i2], gd = list[i3];
      float dy, dx;
      dy = yf - ga.x; dx = xf - ga.y; md2 = fminf(md2, fmaf(dy, dy, dx * dx));
      dy = yf - gb.x; dx = xf - gb.y; md2 = fminf(md2, fmaf(dy, dy, dx * dx));
      dy = yf - gc.x; dx = xf - gc.y; md2 = fminf(md2, fmaf(dy, dy, dx * dx));
      dy = yf - gd.x; dx = xf - gd.y; md2 = fminf(md2, fmaf(dy, dy, dx * dx));
    }
    float s1 = p * __builtin_amdgcn_sqrtf(md2);
    float s0 = p;
#pragma unroll
    for (int s = 1; s < 64; s <<= 1) {
      s1 += __shfl_xor(s1, s, 64);
      s0 += __shfl_xor(s0, s, 64);
    }
    if (lane == 0) { ws1[wave] = s1; ws0[wave] = s0; }
    __syncthreads();
    if (tid == 0)
      partials[b * TILES + tile] =
          make_float2(ws1[0] + ws1[1] + ws1[2] + ws1[3],
                      ws0[0] + ws0[1] + ws0[2] + ws0[3]);
  } else {
    // ---- term 2: one wave per gt; pass-A 16x16 window + guarded exact refine ----
    const int2* gtb = (const int2*)(gt + b * M_GT * 2);
    const int j = (xb - TILES) * 4 + wave;
    int2 g = gtb[j];
    const int gy = g.x, gx = g.y;
    float vmin = BIGF;
#pragma unroll
    for (int k = 0; k < 4; ++k) {
      int idx = k * 64 + lane;
      int oy  = (idx >> 4) - 8;
      int ox  = (idx & 15) - 8;
      int y = gy + oy, x = gx + ox;
      if ((unsigned)y < H_IMG && (unsigned)x < W_IMG) {
        float p   = prob[b * N_PIX + y * W_IMG + x];
        float p2  = p * p;
        float w   = 1.0f / (p2 * p2 + C_DEN);
        float fdy = (float)oy, fdx = (float)ox;
        float d   = __builtin_amdgcn_sqrtf(fmaf(fdy, fdy, fdx * fdx));
        vmin = fminf(vmin, fmaf(d, w, EPS * w));   // (d+eps)/(p^4+eps/maxd)
      }
    }
#pragma unroll
    for (int s = 1; s < 64; s <<= 1) vmin = fminf(vmin, __shfl_xor(vmin, s, 64));
    // winner has d <= U*(1+3e-9); if R <= 7 the disk was inside the scanned window
    float Rf = vmin * 1.000001f + 0.01f;
    if (Rf > 7.0f) {                               // wave-uniform branch
      Rf = fminf(Rf, 363.0f);
      int Ri = (int)Rf + 1;
      for (int yy = gy - Ri; yy <= gy + Ri; ++yy) {
        if ((unsigned)yy >= H_IMG) continue;
        float fdy = (float)(yy - gy);
        float dy2 = fdy * fdy;
        for (int xc = 0; xc <= 2 * Ri; xc += 64) {
          int xx = gx - Ri + xc + lane;
          if ((unsigned)xx < W_IMG) {
            float p   = prob[b * N_PIX + yy * W_IMG + xx];
            float p2  = p * p;
            float w   = 1.0f / (p2 * p2 + C_DEN);
            float fdx = (float)(xx - gx);
            float d   = __builtin_amdgcn_sqrtf(fmaf(fdx, fdx, dy2));
            vmin = fminf(vmin, fmaf(d, w, EPS * w));
          }
        }
      }
#pragma unroll
      for (int s = 1; s < 64; s <<= 1) vmin = fminf(vmin, __shfl_xor(vmin, s, 64));
    }
    if (lane == 0) minU[b * M_GT + j] = vmin;      // sole owner
  }
}

// ---------------- K2: single-block fixed-order final reduction ----------------
__global__ __launch_bounds__(256) void whd_final(
    const float* __restrict__ minU,
    const float2* __restrict__ partials,
    float* __restrict__ out)
{
  const int tid  = threadIdx.x;
  const int lane = tid & 63;
  const int b    = tid >> 6;        // one wave per sample
  __shared__ float t1[NB], t2[NB];

  // term 2: mean of clipped per-gt mins (8 per lane, fixed order)
  float s2 = 0.f;
#pragma unroll
  for (int u = 0; u < M_GT / 64; ++u) {
    float v = minU[b * M_GT + u * 64 + lane];
    v = fminf(fmaxf(v, 0.f), MAXD);
    s2 += v;
  }
  // term 1: 256 per-tile partials (4 per lane, fixed order)
  float s1 = 0.f, s0 = 0.f;
#pragma unroll
  for (int u = 0; u < TILES / 64; ++u) {
    float2 pp = partials[b * TILES + u * 64 + lane];
    s1 += pp.x; s0 += pp.y;
  }
#pragma unroll
  for (int m = 1; m < 64; m <<= 1) {
    s2 += __shfl_xor(s2, m, 64);
    s1 += __shfl_xor(s1, m, 64);
    s0 += __shfl_xor(s0, m, 64);
  }
  if (lane == 0) {
    t1[b] = s1 / (s0 + EPS);
    t2[b] = s2 / (float)M_GT;
  }
  __syncthreads();
  if (tid == 0) {
    float a = 0.f, c = 0.f;
    for (int i = 0; i < NB; ++i) { a += t1[i]; c += t2[i]; }
    out[0] = a * 0.25f + c * 0.25f;
  }
}

extern "C" void kernel_launch(void* const* d_in, const int* in_sizes, int n_in,
                              void* d_out, int out_size, void* d_ws, size_t ws_size,
                              hipStream_t stream) {
  const float* prob = (const float*)d_in[0];
  const int*   gt   = (const int*)d_in[1];

  char* ws = (char*)d_ws;
  float*  minU     = (float*)ws;                    // NB*512 floats = 8 KB
  float2* partials = (float2*)(ws + 8192);          // NB*256 float2 = 8 KB

  whd_work<<<dim3(BLKX, NB), 256, 0, stream>>>(prob, gt, minU, partials);
  whd_final<<<1, 256, 0, stream>>>(minU, partials, (float*)d_out);
}

// Round 9
// 11.544 us; speedup vs baseline: 9.0995x; 1.0056x over previous
//
#include <hip/hip_runtime.h>

#define W_IMG 256
#define H_IMG 256
#define N_PIX 65536
#define M_GT  512
#define NB    4
#define TILES 256               // 256 term-1 blocks/sample: one 16x16 tile each
#define T2BLK 128               // 128 term-2 blocks/sample: 4 waves x 1 gt = 512 gt
#define BLKX  (TILES + T2BLK)   // 384 blocks per sample

constexpr float EPS   = 1e-6f;
constexpr float MAXD  = 362.03867196751236f;
constexpr float C_DEN = 2.7621343e-09f;   // float(EPS / max_dist)
#define BIGF 3.0e38f

// ---------------- K1: all pair work; every output slot has one owner ----------------
__global__ __launch_bounds__(256) void whd_work(
    const float* __restrict__ prob, const int* __restrict__ gt,
    float* __restrict__ minU, float2* __restrict__ partials)
{
  const int b    = blockIdx.y;
  const int xb   = blockIdx.x;
  const int tid  = threadIdx.x;
  const int lane = tid & 63;
  const int wave = tid >> 6;

  if (xb < TILES) {
    // ---- term 1: one 16x16 pixel tile; wave-autonomous candidate pruning ----
    const int tile = xb;
    const int row0 = (tile >> 4) << 4;
    const int col0 = (tile & 15) << 4;
    __shared__ float2 list[4][M_GT];   // wave-private candidate lists
    __shared__ float  ws1[4], ws0[4];

    // prefetch this thread's pixel early: latency hides under the prune phase
    const int py = row0 + (tid >> 4);
    const int px = col0 + (tid & 15);
    const float p = prob[b * N_PIX + py * W_IMG + px];

    // each lane loads ALL-512-covering slice: 8 gt points (4x dwordx4)
    const int4* gt4 = (const int4*)(gt + b * M_GT * 2);   // int4 = 2 points
    int4 q0 = gt4[4 * lane + 0];
    int4 q1 = gt4[4 * lane + 1];
    int4 q2 = gt4[4 * lane + 2];
    int4 q3 = gt4[4 * lane + 3];
    float gy[8], gx[8];
    gy[0] = (float)q0.x; gx[0] = (float)q0.y;  gy[1] = (float)q0.z; gx[1] = (float)q0.w;
    gy[2] = (float)q1.x; gx[2] = (float)q1.y;  gy[3] = (float)q1.z; gx[3] = (float)q1.w;
    gy[4] = (float)q2.x; gx[4] = (float)q2.y;  gy[5] = (float)q2.z; gx[5] = (float)q2.w;
    gy[6] = (float)q3.x; gx[6] = (float)q3.y;  gy[7] = (float)q3.z; gx[7] = (float)q3.w;

    const float cy = row0 + 7.5f, cx = col0 + 7.5f;
    float d2c[8], m = BIGF;
#pragma unroll
    for (int k = 0; k < 8; ++k) {
      float dy = gy[k] - cy, dx = gx[k] - cx;
      d2c[k] = fmaf(dy, dy, dx * dx);            // exact: half-int grid < 2^18
      m = fminf(m, d2c[k]);
    }
#pragma unroll
    for (int s = 1; s < 64; s <<= 1) m = fminf(m, __shfl_xor(m, s, 64));
    // m == true min over all 512 gt (each wave saw every point)
    // candidate iff dcenter <= dmin_center + 2*half_diag (margin >> all rounding)
    float rT = __builtin_amdgcn_sqrtf(m) + 21.3f;
    float T  = rT * rT + 0.5f;

    // wave-private compaction: 8 ballots + prefix popc, no atomics, no barrier
    unsigned long long lt = (1ull << lane) - 1ull;
    int tot = 0;
#pragma unroll
    for (int k = 0; k < 8; ++k) {
      bool pr = d2c[k] <= T;
      unsigned long long mk = __ballot(pr);
      if (pr) list[wave][tot + __popcll(mk & lt)] = make_float2(gy[k], gx[k]);
      tot += __popcll(mk);
    }
    const int ncand = tot;                       // >= 1 (nearest gt always passes)
    // within-wave LDS write->read: compiler-inserted lgkmcnt suffices (one writer wave)

    const float yf = (float)py, xf = (float)px;
    float md2 = BIGF;
    const int nc4 = (ncand + 3) & ~3;
    for (int c = 0; c < nc4; c += 4) {           // x4 unroll, clamped (uniform) idx
      int i1 = min(c + 1, ncand - 1);
      int i2 = min(c + 2, ncand - 1);
      int i3 = min(c + 3, ncand - 1);
      float2 ga = list[wave][c],  gb = list[wave][i1];   // broadcast reads
      float2 gc = list[wave][i2], gd = list[wave][i3];
      float dy, dx;
      dy = yf - ga.x; dx = xf - ga.y; md2 = fminf(md2, fmaf(dy, dy, dx * dx));
      dy = yf - gb.x; dx = xf - gb.y; md2 = fminf(md2, fmaf(dy, dy, dx * dx));
      dy = yf - gc.x; dx = xf - gc.y; md2 = fminf(md2, fmaf(dy, dy, dx * dx));
      dy = yf - gd.x; dx = xf - gd.y; md2 = fminf(md2, fmaf(dy, dy, dx * dx));
    }
    float s1 = p * __builtin_amdgcn_sqrtf(md2);
    float s0 = p;
#pragma unroll
    for (int s = 1; s < 64; s <<= 1) {
      s1 += __shfl_xor(s1, s, 64);
      s0 += __shfl_xor(s0, s, 64);
    }
    if (lane == 0) { ws1[wave] = s1; ws0[wave] = s0; }
    __syncthreads();                             // the ONLY block-wide barrier
    if (tid == 0)
      partials[b * TILES + tile] =
          make_float2(ws1[0] + ws1[1] + ws1[2] + ws1[3],
                      ws0[0] + ws0[1] + ws0[2] + ws0[3]);
  } else {
    // ---- term 2: one wave per gt; pass-A 16x16 window + guarded exact refine ----
    const int2* gtb = (const int2*)(gt + b * M_GT * 2);
    const int j = (xb - TILES) * 4 + wave;
    int2 g = gtb[j];
    const int gy = g.x, gx = g.y;
    float vmin = BIGF;
#pragma unroll
    for (int k = 0; k < 4; ++k) {
      int idx = k * 64 + lane;
      int oy  = (idx >> 4) - 8;
      int ox  = (idx & 15) - 8;
      int y = gy + oy, x = gx + ox;
      if ((unsigned)y < H_IMG && (unsigned)x < W_IMG) {
        float p   = prob[b * N_PIX + y * W_IMG + x];
        float p2  = p * p;
        float w   = 1.0f / (p2 * p2 + C_DEN);
        float fdy = (float)oy, fdx = (float)ox;
        float d   = __builtin_amdgcn_sqrtf(fmaf(fdy, fdy, fdx * fdx));
        vmin = fminf(vmin, fmaf(d, w, EPS * w));   // (d+eps)/(p^4+eps/maxd)
      }
    }
#pragma unroll
    for (int s = 1; s < 64; s <<= 1) vmin = fminf(vmin, __shfl_xor(vmin, s, 64));
    // winner has d <= U*(1+3e-9); if R <= 7 the disk was inside the scanned window
    float Rf = vmin * 1.000001f + 0.01f;
    if (Rf > 7.0f) {                               // wave-uniform branch
      Rf = fminf(Rf, 363.0f);
      int Ri = (int)Rf + 1;
      for (int yy = gy - Ri; yy <= gy + Ri; ++yy) {
        if ((unsigned)yy >= H_IMG) continue;
        float fdy = (float)(yy - gy);
        float dy2 = fdy * fdy;
        for (int xc = 0; xc <= 2 * Ri; xc += 64) {
          int xx = gx - Ri + xc + lane;
          if ((unsigned)xx < W_IMG) {
            float p   = prob[b * N_PIX + yy * W_IMG + xx];
            float p2  = p * p;
            float w   = 1.0f / (p2 * p2 + C_DEN);
            float fdx = (float)(xx - gx);
            float d   = __builtin_amdgcn_sqrtf(fmaf(fdx, fdx, dy2));
            vmin = fminf(vmin, fmaf(d, w, EPS * w));
          }
        }
      }
#pragma unroll
      for (int s = 1; s < 64; s <<= 1) vmin = fminf(vmin, __shfl_xor(vmin, s, 64));
    }
    if (lane == 0) minU[b * M_GT + j] = vmin;      // sole owner
  }
}

// ---------------- K2: single-block fixed-order final reduction ----------------
__global__ __launch_bounds__(256) void whd_final(
    const float* __restrict__ minU,
    const float2* __restrict__ partials,
    float* __restrict__ out)
{
  const int tid  = threadIdx.x;
  const int lane = tid & 63;
  const int b    = tid >> 6;        // one wave per sample
  __shared__ float t1[NB], t2[NB];

  // term 2: mean of clipped per-gt mins (8 per lane, fixed order)
  float s2 = 0.f;
#pragma unroll
  for (int u = 0; u < M_GT / 64; ++u) {
    float v = minU[b * M_GT + u * 64 + lane];
    v = fminf(fmaxf(v, 0.f), MAXD);
    s2 += v;
  }
  // term 1: 256 per-tile partials (4 per lane, fixed order)
  float s1 = 0.f, s0 = 0.f;
#pragma unroll
  for (int u = 0; u < TILES / 64; ++u) {
    float2 pp = partials[b * TILES + u * 64 + lane];
    s1 += pp.x; s0 += pp.y;
  }
#pragma unroll
  for (int m = 1; m < 64; m <<= 1) {
    s2 += __shfl_xor(s2, m, 64);
    s1 += __shfl_xor(s1, m, 64);
    s0 += __shfl_xor(s0, m, 64);
  }
  if (lane == 0) {
    t1[b] = s1 / (s0 + EPS);
    t2[b] = s2 / (float)M_GT;
  }
  __syncthreads();
  if (tid == 0) {
    float a = 0.f, c = 0.f;
    for (int i = 0; i < NB; ++i) { a += t1[i]; c += t2[i]; }
    out[0] = a * 0.25f + c * 0.25f;
  }
}

extern "C" void kernel_launch(void* const* d_in, const int* in_sizes, int n_in,
                              void* d_out, int out_size, void* d_ws, size_t ws_size,
                              hipStream_t stream) {
  const float* prob = (const float*)d_in[0];
  const int*   gt   = (const int*)d_in[1];

  char* ws = (char*)d_ws;
  float*  minU     = (float*)ws;                    // NB*512 floats = 8 KB
  float2* partials = (float2*)(ws + 8192);          // NB*256 float2 = 8 KB

  whd_work<<<dim3(BLKX, NB), 256, 0, stream>>>(prob, gt, minU, partials);
  whd_final<<<1, 256, 0, stream>>>(minU, partials, (float*)d_out);
}